// Round 3
// baseline (737.569 us; speedup 1.0000x reference)
//
#include <hip/hip_runtime.h>

// MoE top-2 layer, MI355X — round 5.
// r5 changes vs r4 (717 us; proj 171, FETCH 96MB=minimal, MfmaUtil 17%):
//   * Double-buffered LDS K-loop (T3 "minimum 2-phase" recipe) in BOTH GEMMs.
//     r4 proved proj is latency-bound, not BW-bound: swizzle cut FETCH 3.2x
//     with ZERO time change. The single-buffer loop exposes the full
//     global->LDS latency every K-step (stage -> barrier+vmcnt(0) -> compute
//     -> barrier). New loop: STAGE(t+1) into alternate buffer BEFORE
//     computing tile t; ONE barrier per K-step (compiler inserts vmcnt(0)
//     before it). Load latency hides under ds_read+MFMA of current tile.
//     LDS 16 -> 32 KB/block: occupancy cap 10 -> 5 blocks/CU (>= grid supply).
//   * Keep: XCD chunked swizzle (r4, FETCH 310->96MB), KSPLIT=2 (r3 lesson:
//     4 regressed via atomic traffic), fast gelu (r3).
//
// All GEMM operands pre-packed fp16 in [kb][row][32] layout (kb = k/32) so
// every 128x32 tile is one contiguous 8KB block -> global_load_lds width=16
// for BOTH operands.
//
// N=4096 tokens, C=1024, E=8, H=4096, top-2. NPC=9216 slot capacity
// (worst-case per-expert 128-alignment). ws required ~162 MB.

#define NTOK  4096
#define CDIM  1024
#define HDIM  4096
#define NEXP  8
#define NPC   9216
#define MAXMT 72
#define KB_C  32     // CDIM/32
#define KB_H  128    // HDIM/32
#define KSPLIT 2     // proj split-K slices

// swizzle chunk sizes (blocks per XCD)
#define FC_TOTAL (32 * MAXMT)          // 2304
#define FC_CHUNK (FC_TOTAL / 8)        // 288
#define PJ_TOTAL (8 * MAXMT * KSPLIT)  // 1152
#define PJ_CHUNK (PJ_TOTAL / 8)        // 144

typedef _Float16 half8 __attribute__((ext_vector_type(8)));
typedef float    f32x4 __attribute__((ext_vector_type(4)));

// async global->LDS, 16B per lane. LDS dest = wave-uniform base + lane*16;
// global source address is per-lane.
#define ASYNC_CP16(gp, lp)                                                         \
  __builtin_amdgcn_global_load_lds(                                                \
      (const __attribute__((address_space(1))) unsigned int*)(gp),                 \
      (__attribute__((address_space(3))) unsigned int*)(lp), 16, 0, 0)

// stage one 128x32 A-tile + 128x32 B-tile (8KB each) for K-block kb into the
// given wave-sliced LDS bases. ga/gb per-lane global addrs include soff.
#define STAGE(kb, LA, LB, BSTRIDE)                                                 \
  {                                                                                \
    const char* ga_ = gA0 + (size_t)(kb) * (NPC * 64) + soff;                      \
    const char* gb_ = gB0 + (size_t)(kb) * ((BSTRIDE) * 64) + soff;                \
    ASYNC_CP16(ga_,        LA);                                                    \
    ASYNC_CP16(ga_ + 1024, LA + 1024);                                             \
    ASYNC_CP16(gb_,        LB);                                                    \
    ASYNC_CP16(gb_ + 1024, LB + 1024);                                             \
  }

__device__ __forceinline__ void compute_step(
    const _Float16* __restrict__ AS, const _Float16* __restrict__ BS,
    int wm, int wn, int l16, int lq, f32x4 (&acc)[4][4])
{
    half8 af[4], bfv[4];
    #pragma unroll
    for (int i = 0; i < 4; ++i) af[i]  = *(const half8*)&AS[(wm + i * 16 + l16) * 32 + lq * 8];
    #pragma unroll
    for (int j = 0; j < 4; ++j) bfv[j] = *(const half8*)&BS[(wn + j * 16 + l16) * 32 + lq * 8];
    #pragma unroll
    for (int i = 0; i < 4; ++i)
        #pragma unroll
        for (int j = 0; j < 4; ++j)
            acc[i][j] = __builtin_amdgcn_mfma_f32_16x16x32_f16(af[i], bfv[j], acc[i][j], 0, 0, 0);
}

__device__ __forceinline__ float gelu_new(float x) {
    // 0.5x(1+tanh(u)) == x * sigmoid(2u); robust at extremes.
    const float c = 0.7978845608028654f;  // sqrt(2/pi)
    float u = c * (x + 0.044715f * x * x * x);
    return x / (1.0f + __expf(-2.0f * u));
}

// ---------------- utility ----------------

__global__ void zero_init(unsigned int* __restrict__ pairs,   // pair_tok+pair_gate
                          unsigned int* __restrict__ counts) {
    int i = blockIdx.x * 256 + threadIdx.x;
    if (i < 2 * NPC) pairs[i] = 0u;
    if (i < NEXP) counts[i] = 0u;
}

// ---------------- routing ----------------

__global__ __launch_bounds__(256) void router_kernel(
    const float* __restrict__ x, const float* __restrict__ rw,
    int* __restrict__ tok_e, float* __restrict__ tok_w, int* __restrict__ counts)
{
    int wave = threadIdx.x >> 6, lane = threadIdx.x & 63;
    int n = blockIdx.x * 4 + wave;
    const float* xr = x + (size_t)n * CDIM;
    float acc[NEXP];
    #pragma unroll
    for (int e = 0; e < NEXP; ++e) acc[e] = 0.f;
    for (int c = lane; c < CDIM; c += 64) {
        float xv = xr[c];
        #pragma unroll
        for (int e = 0; e < NEXP; ++e) acc[e] = fmaf(xv, rw[e * CDIM + c], acc[e]);
    }
    #pragma unroll
    for (int e = 0; e < NEXP; ++e) {
        float v = acc[e];
        #pragma unroll
        for (int off = 32; off > 0; off >>= 1) v += __shfl_down(v, off);
        acc[e] = v;
    }
    if (lane == 0) {
        float l0 = -3.0e38f, l1 = -3.0e38f; int b0 = 0, b1 = 0;
        #pragma unroll
        for (int e = 0; e < NEXP; ++e) {
            float v = acc[e];
            if (v > l0)      { l1 = l0; b1 = b0; l0 = v; b0 = e; }
            else if (v > l1) { l1 = v; b1 = e; }
        }
        float t  = expf(l1 - l0);            // l1 <= l0, stable
        float w0 = 1.f / (1.f + t);
        float w1 = t  / (1.f + t);
        tok_e[n * 2]     = b0;  tok_e[n * 2 + 1] = b1;
        tok_w[n * 2]     = w0;  tok_w[n * 2 + 1] = w1;
        atomicAdd(&counts[b0], 1);
        atomicAdd(&counts[b1], 1);
    }
}

__global__ void plan_kernel(const int* __restrict__ counts, int* __restrict__ cursors,
                            int* __restrict__ mtiles, int* __restrict__ tile_expert)
{
    if (threadIdx.x == 0 && blockIdx.x == 0) {
        int b = 0;
        for (int e = 0; e < NEXP; ++e) {
            cursors[e] = b;
            int tiles = (counts[e] + 127) >> 7;
            for (int t = 0; t < tiles; ++t) tile_expert[(b >> 7) + t] = e;
            b += tiles << 7;
        }
        *mtiles = b >> 7;
        for (int t = b >> 7; t < MAXMT; ++t) tile_expert[t] = 0;
    }
}

__global__ void assign_kernel(const int* __restrict__ tok_e, const float* __restrict__ tok_w,
                              int* __restrict__ cursors,
                              int* __restrict__ pair_tok, float* __restrict__ pair_gate)
{
    int n = blockIdx.x * 256 + threadIdx.x;  // exactly NTOK threads
    #pragma unroll
    for (int k = 0; k < 2; ++k) {
        int e = tok_e[n * 2 + k];
        int slot = atomicAdd(&cursors[e], 1);
        pair_tok[slot]  = n;
        pair_gate[slot] = tok_w[n * 2 + k];
    }
}

// ---------------- A gather+convert into packed layout ----------------
// xg[kb][slot][kk] = fp16(x[pair_tok[slot]][kb*32+kk]); pad slots -> token 0.

__global__ __launch_bounds__(256) void gather_x_kernel(
    const float* __restrict__ x, const int* __restrict__ pair_tok,
    _Float16* __restrict__ xg)
{
    int o = blockIdx.x * 256 + threadIdx.x;          // KB_C * NPC * 4 threads
    int kb   = o / (NPC * 4);
    int rem  = o - kb * (NPC * 4);
    int slot = rem >> 2;
    int c    = (rem & 3) * 8;
    int tok  = pair_tok[slot];
    const float* src = x + (size_t)tok * CDIM + kb * 32 + c;
    float4 a = *(const float4*)src;
    float4 b = *(const float4*)(src + 4);
    half8 h;
    h[0] = (_Float16)a.x; h[1] = (_Float16)a.y; h[2] = (_Float16)a.z; h[3] = (_Float16)a.w;
    h[4] = (_Float16)b.x; h[5] = (_Float16)b.y; h[6] = (_Float16)b.z; h[7] = (_Float16)b.w;
    *(half8*)(xg + ((size_t)kb * NPC + slot) * 32 + c) = h;
}

// ---------------- weight transpose+convert ----------------
// w [E][K][N] fp32  ->  wt [E][K/32][N][32] fp16  (wt[e][kb][n][kk] = w[e][kb*32+kk][n])
// Block handles 32k x 64n tile via LDS. Reads and writes fully coalesced.

__global__ __launch_bounds__(256) void transpose_cvt_kernel(
    const float* __restrict__ w, _Float16* __restrict__ wt, int K, int N)
{
    __shared__ float tile[32][68];                   // 68: 16B-aligned rows, pad
    const int e = blockIdx.z, k0 = blockIdx.y * 32, n0 = blockIdx.x * 64;
    const float* src = w + ((size_t)e * K + k0) * N + n0;
    const int t = threadIdx.x;
    #pragma unroll
    for (int f = t; f < 512; f += 256) {             // 512 float4 = 32x64 floats
        int k = f >> 4, nc = (f & 15) * 4;
        *(float4*)&tile[k][nc] = *(const float4*)(src + (size_t)k * N + nc);
    }
    __syncthreads();
    int n = t >> 2, c2 = (t & 3) * 8;
    half8 h;
    #pragma unroll
    for (int q = 0; q < 8; ++q) h[q] = (_Float16)tile[c2 + q][n];
    int KB = K >> 5;
    _Float16* dst = wt + (((size_t)e * KB + (k0 >> 5)) * N + (n0 + n)) * 32 + c2;
    *(half8*)dst = h;
}

// ---------------- GEMM 1: hb = gelu(xg @ wt_fc + b_fc)  (packed in/out) ----------------
// 128x128 tile, BK=32, 4 waves x (4x4 mfma_f32_16x16x32_f16), double-buffered.

__global__ __launch_bounds__(256) void gemm_fc_kernel(
    const _Float16* __restrict__ xg,     // packed [KB_C][NPC][32]
    const _Float16* __restrict__ wt,     // packed [E][KB_C][HDIM][32]
    const float*    __restrict__ b_fc,   // [E][HDIM]
    const int*      __restrict__ tile_expert,
    const int*      __restrict__ mtiles,
    _Float16*       __restrict__ hb)     // packed [KB_H][NPC][32]
{
    // ---- XCD chunked swizzle (bijective: FC_TOTAL % 8 == 0) ----
    const unsigned flat = blockIdx.y * 32u + blockIdx.x;
    const unsigned logical = (flat & 7u) * FC_CHUNK + (flat >> 3);
    const int nt = logical & 31;          // 32 nt, fastest
    const int mt = logical >> 5;
    if (mt >= *mtiles) return;
    const int e  = tile_expert[mt];
    const int m0 = mt << 7, n0 = nt << 7;

    __shared__ _Float16 As0[128 * 32], Bs0[128 * 32];
    __shared__ _Float16 As1[128 * 32], Bs1[128 * 32];

    const int tid = threadIdx.x;
    const int lane = tid & 63, wv = tid >> 6;
    const int wm = (wv >> 1) * 64, wn = (wv & 1) * 64;
    const int l16 = lane & 15, lq = lane >> 4;

    const char* gA0 = (const char*)xg + (size_t)m0 * 64;
    const char* gB0 = (const char*)wt + ((size_t)e * KB_C * HDIM + n0) * 64;
    const int soff = wv * 2048 + lane * 16;
    char* lA0 = (char*)As0 + wv * 2048;  char* lB0 = (char*)Bs0 + wv * 2048;
    char* lA1 = (char*)As1 + wv * 2048;  char* lB1 = (char*)Bs1 + wv * 2048;

    f32x4 acc[4][4];
    #pragma unroll
    for (int i = 0; i < 4; ++i)
        #pragma unroll
        for (int j = 0; j < 4; ++j) { acc[i][j][0]=0.f; acc[i][j][1]=0.f; acc[i][j][2]=0.f; acc[i][j][3]=0.f; }

    STAGE(0, lA0, lB0, HDIM);
    __syncthreads();                       // compiler adds vmcnt(0)
    for (int kb = 0; kb < KB_C; kb += 2) {
        STAGE(kb + 1, lA1, lB1, HDIM);     // kb+1 <= KB_C-1 always (KB_C even)
        compute_step(As0, Bs0, wm, wn, l16, lq, acc);
        __syncthreads();                   // buf1 staged; buf0 free
        if (kb + 2 < KB_C) STAGE(kb + 2, lA0, lB0, HDIM);
        compute_step(As1, Bs1, wm, wn, l16, lq, acc);
        __syncthreads();                   // buf0 staged; buf1 free
    }

    float bias[4];
    #pragma unroll
    for (int j = 0; j < 4; ++j) bias[j] = b_fc[e * HDIM + n0 + wn + j * 16 + l16];
    #pragma unroll
    for (int i = 0; i < 4; ++i) {
        #pragma unroll
        for (int r = 0; r < 4; ++r) {
            int slot = m0 + wm + i * 16 + lq * 4 + r;   // D row = quad*4 + reg
            #pragma unroll
            for (int j = 0; j < 4; ++j) {
                int n = n0 + wn + j * 16 + l16;          // D col = lane&15
                float v = gelu_new(acc[i][j][r] + bias[j]);
                hb[((size_t)(n >> 5) * NPC + slot) * 32 + (n & 31)] = (_Float16)v;
            }
        }
    }
}

// ---------------- GEMM 2: y[tok] += gate * (hb @ wt_proj + b_proj), split-K=2 ----------------
// Double-buffered like gemm_fc. XCD chunked swizzle.

__global__ __launch_bounds__(256) void gemm_proj_kernel(
    const _Float16* __restrict__ hb,     // packed [KB_H][NPC][32]
    const _Float16* __restrict__ wt,     // packed [E][KB_H][CDIM][32]
    const float*    __restrict__ b_proj, // [E][CDIM]
    const int*      __restrict__ pair_tok,
    const float*    __restrict__ pair_gate,
    const int*      __restrict__ tile_expert,
    const int*      __restrict__ mtiles,
    float*          __restrict__ y)      // [NTOK][CDIM]
{
    // ---- XCD chunked swizzle (bijective: PJ_TOTAL % 8 == 0) ----
    const unsigned flat = (blockIdx.z * MAXMT + blockIdx.y) * 8u + blockIdx.x;
    const unsigned logical = (flat & 7u) * PJ_CHUNK + (flat >> 3);
    const int nt = logical & 7;                       // 8 nt, fastest
    const unsigned t2 = logical >> 3;
    const int mt = t2 % MAXMT;
    const int ks = t2 / MAXMT;                        // split-K slice
    if (mt >= *mtiles) return;
    const int e  = tile_expert[mt];
    const int m0 = mt << 7, n0 = nt << 7;

    __shared__ _Float16 As0[128 * 32], Bs0[128 * 32];
    __shared__ _Float16 As1[128 * 32], Bs1[128 * 32];

    const int tid = threadIdx.x;
    const int lane = tid & 63, wv = tid >> 6;
    const int wm = (wv >> 1) * 64, wn = (wv & 1) * 64;
    const int l16 = lane & 15, lq = lane >> 4;

    const char* gA0 = (const char*)hb + (size_t)m0 * 64;
    const char* gB0 = (const char*)wt + ((size_t)e * KB_H * CDIM + n0) * 64;
    const int soff = wv * 2048 + lane * 16;
    char* lA0 = (char*)As0 + wv * 2048;  char* lB0 = (char*)Bs0 + wv * 2048;
    char* lA1 = (char*)As1 + wv * 2048;  char* lB1 = (char*)Bs1 + wv * 2048;

    f32x4 acc[4][4];
    #pragma unroll
    for (int i = 0; i < 4; ++i)
        #pragma unroll
        for (int j = 0; j < 4; ++j) { acc[i][j][0]=0.f; acc[i][j][1]=0.f; acc[i][j][2]=0.f; acc[i][j][3]=0.f; }

    const int kb_beg = ks * (KB_H / KSPLIT);
    const int kb_end = kb_beg + (KB_H / KSPLIT);
    STAGE(kb_beg, lA0, lB0, CDIM);
    __syncthreads();
    for (int kb = kb_beg; kb < kb_end; kb += 2) {
        STAGE(kb + 1, lA1, lB1, CDIM);
        compute_step(As0, Bs0, wm, wn, l16, lq, acc);
        __syncthreads();
        if (kb + 2 < kb_end) STAGE(kb + 2, lA0, lB0, CDIM);
        compute_step(As1, Bs1, wm, wn, l16, lq, acc);
        __syncthreads();
    }

    float bias[4];
    #pragma unroll
    for (int j = 0; j < 4; ++j)
        bias[j] = (ks == 0) ? b_proj[e * CDIM + n0 + wn + j * 16 + l16] : 0.0f;
    #pragma unroll
    for (int i = 0; i < 4; ++i) {
        #pragma unroll
        for (int r = 0; r < 4; ++r) {
            int slot = m0 + wm + i * 16 + lq * 4 + r;
            float g  = pair_gate[slot];
            if (g != 0.0f) {
                int tok = pair_tok[slot];
                float* dst = y + (size_t)tok * CDIM + n0 + wn + l16;
                #pragma unroll
                for (int j = 0; j < 4; ++j)
                    atomicAdd(&dst[j * 16], (acc[i][j][r] + bias[j]) * g);
            }
        }
    }
}

// ---------------- launch ----------------

extern "C" void kernel_launch(void* const* d_in, const int* in_sizes, int n_in,
                              void* d_out, int out_size, void* d_ws, size_t ws_size,
                              hipStream_t stream) {
    const float* x   = (const float*)d_in[0];
    const float* rw  = (const float*)d_in[1];
    const float* wfc = (const float*)d_in[2];
    const float* bfc = (const float*)d_in[3];
    const float* wpj = (const float*)d_in[4];
    const float* bpj = (const float*)d_in[5];
    float* y = (float*)d_out;

    char* ws = (char*)d_ws;
    // workspace layout (bytes), total ~161.7 MB
    _Float16* xg  = (_Float16*)(ws);                    // 18,874,368  [KB_C][NPC][32]
    _Float16* hb  = (_Float16*)(ws + 18874368);         // 75,497,472  [KB_H][NPC][32]
    _Float16* wt  = (_Float16*)(ws + 94371840);         // 67,108,864  shared fc/proj
    char* meta = ws + 161480704;
    int*   pair_tok    = (int*)  (meta);                //  36,864
    float* pair_gate   = (float*)(meta + 36864);        //  36,864 (contiguous after pair_tok)
    int*   tok_e       = (int*)  (meta + 73728);        //  32,768
    float* tok_w       = (float*)(meta + 106496);       //  32,768
    int*   counts      = (int*)  (meta + 139264);       // 8
    int*   cursors     = counts + 8;                    // 8
    int*   mtiles      = cursors + 8;                   // 1 (+pad)
    int*   tile_expert = mtiles + 2;                    // 72

    hipMemsetAsync(y, 0, (size_t)NTOK * CDIM * sizeof(float), stream);
    zero_init<<<(2 * NPC) / 256, 256, 0, stream>>>((unsigned int*)pair_tok,
                                                   (unsigned int*)counts);

    router_kernel<<<1024, 256, 0, stream>>>(x, rw, tok_e, tok_w, counts);
    plan_kernel<<<1, 64, 0, stream>>>(counts, cursors, mtiles, tile_expert);
    assign_kernel<<<16, 256, 0, stream>>>(tok_e, tok_w, cursors, pair_tok, pair_gate);
    gather_x_kernel<<<KB_C * NPC * 4 / 256, 256, 0, stream>>>(x, pair_tok, xg);

    // fc: transpose w_fc -> wt, then GEMM into hb
    transpose_cvt_kernel<<<dim3(HDIM / 64, CDIM / 32, NEXP), 256, 0, stream>>>(wfc, wt, CDIM, HDIM);
    gemm_fc_kernel<<<dim3(HDIM / 128, MAXMT), 256, 0, stream>>>(
        xg, wt, bfc, tile_expert, mtiles, hb);

    // proj: transpose w_proj -> wt (reuse buffer), then GEMM into y
    transpose_cvt_kernel<<<dim3(CDIM / 64, HDIM / 32, NEXP), 256, 0, stream>>>(wpj, wt, HDIM, CDIM);
    gemm_proj_kernel<<<dim3(CDIM / 128, MAXMT, KSPLIT), 256, 0, stream>>>(
        hb, wt, bpj, pair_tok, pair_gate, tile_expert, mtiles, y);
}

// Round 4
// 697.174 us; speedup vs baseline: 1.0579x; 1.0579x over previous
//
#include <hip/hip_runtime.h>

// MoE top-2 layer, MI355X — round 6.
// r6 changes vs r5 (737 us; proj 156, fc regressed ~35 via LDS occupancy cap):
//   * Counted-vmcnt software pipeline (T4) in BOTH GEMMs. r5's dbuf used
//     __syncthreads(), whose semantics force s_waitcnt vmcnt(0) before every
//     barrier -- draining the STAGE(t+1) just issued. Now: raw
//     __builtin_amdgcn_s_barrier() + inline-asm s_waitcnt vmcnt(4), so the
//     next tile's 4 global_load_lds stay IN FLIGHT across the barrier
//     (m218 pattern: counted vs drain0 = +38..73%).
//     Safety: (1) per-wave vmcnt(4) then s_barrier publishes all waves'
//     STAGE(t) before any ds_read; (2) sched_barrier(0) after the MFMA
//     cluster pins ds_reads+lgkm waits before barrier-2, so no wave still
//     reads a buffer when it is re-staged (rule #18 analog); (3) loop vmcnt
//     counts only STAGE loads (all other vmem is pre/post loop).
//   * Keep: XCD chunked swizzle (r4: FETCH 310->96MB), KSPLIT=2, fast gelu,
//     dbuf LDS 32KB (cap 5 blocks/CU >= supply for both GEMMs).
//
// All GEMM operands pre-packed fp16 in [kb][row][32] layout (kb = k/32) so
// every 128x32 tile is one contiguous 8KB block -> global_load_lds width=16
// for BOTH operands.
//
// N=4096 tokens, C=1024, E=8, H=4096, top-2. NPC=9216 slot capacity
// (worst-case per-expert 128-alignment). ws required ~162 MB.

#define NTOK  4096
#define CDIM  1024
#define HDIM  4096
#define NEXP  8
#define NPC   9216
#define MAXMT 72
#define KB_C  32     // CDIM/32
#define KB_H  128    // HDIM/32
#define KSPLIT 2     // proj split-K slices

// swizzle chunk sizes (blocks per XCD)
#define FC_TOTAL (32 * MAXMT)          // 2304
#define FC_CHUNK (FC_TOTAL / 8)        // 288
#define PJ_TOTAL (8 * MAXMT * KSPLIT)  // 1152
#define PJ_CHUNK (PJ_TOTAL / 8)        // 144

typedef _Float16 half8 __attribute__((ext_vector_type(8)));
typedef float    f32x4 __attribute__((ext_vector_type(4)));

// async global->LDS, 16B per lane. LDS dest = wave-uniform base + lane*16;
// global source address is per-lane.
#define ASYNC_CP16(gp, lp)                                                         \
  __builtin_amdgcn_global_load_lds(                                                \
      (const __attribute__((address_space(1))) unsigned int*)(gp),                 \
      (__attribute__((address_space(3))) unsigned int*)(lp), 16, 0, 0)

// stage one 128x32 A-tile + 128x32 B-tile (8KB each) for K-block kb into the
// given wave-sliced LDS bases (4 gload_lds = 4 vmcnt events per wave).
#define STAGE(kb, LA, LB, BSTRIDE)                                                 \
  {                                                                                \
    const char* ga_ = gA0 + (size_t)(kb) * (NPC * 64) + soff;                      \
    const char* gb_ = gB0 + (size_t)(kb) * ((BSTRIDE) * 64) + soff;                \
    ASYNC_CP16(ga_,        LA);                                                    \
    ASYNC_CP16(ga_ + 1024, LA + 1024);                                             \
    ASYNC_CP16(gb_,        LB);                                                    \
    ASYNC_CP16(gb_ + 1024, LB + 1024);                                             \
  }

#define WAITV(N) asm volatile("s_waitcnt vmcnt(" #N ")" ::: "memory")
#define BAR()    __builtin_amdgcn_s_barrier()
#define SCHED0() __builtin_amdgcn_sched_barrier(0)

__device__ __forceinline__ void compute_step(
    const _Float16* __restrict__ AS, const _Float16* __restrict__ BS,
    int wm, int wn, int l16, int lq, f32x4 (&acc)[4][4])
{
    half8 af[4], bfv[4];
    #pragma unroll
    for (int i = 0; i < 4; ++i) af[i]  = *(const half8*)&AS[(wm + i * 16 + l16) * 32 + lq * 8];
    #pragma unroll
    for (int j = 0; j < 4; ++j) bfv[j] = *(const half8*)&BS[(wn + j * 16 + l16) * 32 + lq * 8];
    #pragma unroll
    for (int i = 0; i < 4; ++i)
        #pragma unroll
        for (int j = 0; j < 4; ++j)
            acc[i][j] = __builtin_amdgcn_mfma_f32_16x16x32_f16(af[i], bfv[j], acc[i][j], 0, 0, 0);
}

// Pipelined K-loop over [kb_beg, kb_end), NS even and >= 4.
// buf0 holds even (t-kb_beg), buf1 odd. vmcnt(4) = "my previous STAGE landed,
// the one after it may still fly". Tail peels with vmcnt(4) then vmcnt(0).
#define PIPE_LOOP(kb_beg, kb_end, BSTRIDE)                                         \
  {                                                                                \
    STAGE((kb_beg),     lA0, lB0, BSTRIDE);                                        \
    STAGE((kb_beg) + 1, lA1, lB1, BSTRIDE);                                        \
    for (int t = (kb_beg); t + 2 < (kb_end); t += 2) {                             \
        WAITV(4); BAR();                                                           \
        compute_step(As0, Bs0, wm, wn, l16, lq, acc);                              \
        SCHED0(); BAR();                                                           \
        STAGE(t + 2, lA0, lB0, BSTRIDE);                                           \
        WAITV(4); BAR();                                                           \
        compute_step(As1, Bs1, wm, wn, l16, lq, acc);                              \
        SCHED0(); BAR();                                                           \
        STAGE(t + 3, lA1, lB1, BSTRIDE);                                           \
    }                                                                              \
    WAITV(4); BAR();                                                               \
    compute_step(As0, Bs0, wm, wn, l16, lq, acc);                                  \
    SCHED0(); BAR();                                                               \
    WAITV(0); BAR();                                                               \
    compute_step(As1, Bs1, wm, wn, l16, lq, acc);                                  \
  }

__device__ __forceinline__ float gelu_new(float x) {
    // 0.5x(1+tanh(u)) == x * sigmoid(2u); robust at extremes.
    const float c = 0.7978845608028654f;  // sqrt(2/pi)
    float u = c * (x + 0.044715f * x * x * x);
    return x / (1.0f + __expf(-2.0f * u));
}

// ---------------- utility ----------------

__global__ void zero_init(unsigned int* __restrict__ pairs,   // pair_tok+pair_gate
                          unsigned int* __restrict__ counts) {
    int i = blockIdx.x * 256 + threadIdx.x;
    if (i < 2 * NPC) pairs[i] = 0u;
    if (i < NEXP) counts[i] = 0u;
}

// ---------------- routing ----------------

__global__ __launch_bounds__(256) void router_kernel(
    const float* __restrict__ x, const float* __restrict__ rw,
    int* __restrict__ tok_e, float* __restrict__ tok_w, int* __restrict__ counts)
{
    int wave = threadIdx.x >> 6, lane = threadIdx.x & 63;
    int n = blockIdx.x * 4 + wave;
    const float* xr = x + (size_t)n * CDIM;
    float acc[NEXP];
    #pragma unroll
    for (int e = 0; e < NEXP; ++e) acc[e] = 0.f;
    for (int c = lane; c < CDIM; c += 64) {
        float xv = xr[c];
        #pragma unroll
        for (int e = 0; e < NEXP; ++e) acc[e] = fmaf(xv, rw[e * CDIM + c], acc[e]);
    }
    #pragma unroll
    for (int e = 0; e < NEXP; ++e) {
        float v = acc[e];
        #pragma unroll
        for (int off = 32; off > 0; off >>= 1) v += __shfl_down(v, off);
        acc[e] = v;
    }
    if (lane == 0) {
        float l0 = -3.0e38f, l1 = -3.0e38f; int b0 = 0, b1 = 0;
        #pragma unroll
        for (int e = 0; e < NEXP; ++e) {
            float v = acc[e];
            if (v > l0)      { l1 = l0; b1 = b0; l0 = v; b0 = e; }
            else if (v > l1) { l1 = v; b1 = e; }
        }
        float t  = expf(l1 - l0);            // l1 <= l0, stable
        float w0 = 1.f / (1.f + t);
        float w1 = t  / (1.f + t);
        tok_e[n * 2]     = b0;  tok_e[n * 2 + 1] = b1;
        tok_w[n * 2]     = w0;  tok_w[n * 2 + 1] = w1;
        atomicAdd(&counts[b0], 1);
        atomicAdd(&counts[b1], 1);
    }
}

__global__ void plan_kernel(const int* __restrict__ counts, int* __restrict__ cursors,
                            int* __restrict__ mtiles, int* __restrict__ tile_expert)
{
    if (threadIdx.x == 0 && blockIdx.x == 0) {
        int b = 0;
        for (int e = 0; e < NEXP; ++e) {
            cursors[e] = b;
            int tiles = (counts[e] + 127) >> 7;
            for (int t = 0; t < tiles; ++t) tile_expert[(b >> 7) + t] = e;
            b += tiles << 7;
        }
        *mtiles = b >> 7;
        for (int t = b >> 7; t < MAXMT; ++t) tile_expert[t] = 0;
    }
}

__global__ void assign_kernel(const int* __restrict__ tok_e, const float* __restrict__ tok_w,
                              int* __restrict__ cursors,
                              int* __restrict__ pair_tok, float* __restrict__ pair_gate)
{
    int n = blockIdx.x * 256 + threadIdx.x;  // exactly NTOK threads
    #pragma unroll
    for (int k = 0; k < 2; ++k) {
        int e = tok_e[n * 2 + k];
        int slot = atomicAdd(&cursors[e], 1);
        pair_tok[slot]  = n;
        pair_gate[slot] = tok_w[n * 2 + k];
    }
}

// ---------------- A gather+convert into packed layout ----------------
// xg[kb][slot][kk] = fp16(x[pair_tok[slot]][kb*32+kk]); pad slots -> token 0.

__global__ __launch_bounds__(256) void gather_x_kernel(
    const float* __restrict__ x, const int* __restrict__ pair_tok,
    _Float16* __restrict__ xg)
{
    int o = blockIdx.x * 256 + threadIdx.x;          // KB_C * NPC * 4 threads
    int kb   = o / (NPC * 4);
    int rem  = o - kb * (NPC * 4);
    int slot = rem >> 2;
    int c    = (rem & 3) * 8;
    int tok  = pair_tok[slot];
    const float* src = x + (size_t)tok * CDIM + kb * 32 + c;
    float4 a = *(const float4*)src;
    float4 b = *(const float4*)(src + 4);
    half8 h;
    h[0] = (_Float16)a.x; h[1] = (_Float16)a.y; h[2] = (_Float16)a.z; h[3] = (_Float16)a.w;
    h[4] = (_Float16)b.x; h[5] = (_Float16)b.y; h[6] = (_Float16)b.z; h[7] = (_Float16)b.w;
    *(half8*)(xg + ((size_t)kb * NPC + slot) * 32 + c) = h;
}

// ---------------- weight transpose+convert ----------------
// w [E][K][N] fp32  ->  wt [E][K/32][N][32] fp16  (wt[e][kb][n][kk] = w[e][kb*32+kk][n])
// Block handles 32k x 64n tile via LDS. Reads and writes fully coalesced.

__global__ __launch_bounds__(256) void transpose_cvt_kernel(
    const float* __restrict__ w, _Float16* __restrict__ wt, int K, int N)
{
    __shared__ float tile[32][68];                   // 68: 16B-aligned rows, pad
    const int e = blockIdx.z, k0 = blockIdx.y * 32, n0 = blockIdx.x * 64;
    const float* src = w + ((size_t)e * K + k0) * N + n0;
    const int t = threadIdx.x;
    #pragma unroll
    for (int f = t; f < 512; f += 256) {             // 512 float4 = 32x64 floats
        int k = f >> 4, nc = (f & 15) * 4;
        *(float4*)&tile[k][nc] = *(const float4*)(src + (size_t)k * N + nc);
    }
    __syncthreads();
    int n = t >> 2, c2 = (t & 3) * 8;
    half8 h;
    #pragma unroll
    for (int q = 0; q < 8; ++q) h[q] = (_Float16)tile[c2 + q][n];
    int KB = K >> 5;
    _Float16* dst = wt + (((size_t)e * KB + (k0 >> 5)) * N + (n0 + n)) * 32 + c2;
    *(half8*)dst = h;
}

// ---------------- GEMM 1: hb = gelu(xg @ wt_fc + b_fc)  (packed in/out) ----------------
// 128x128 tile, BK=32, 4 waves x (4x4 mfma_f32_16x16x32_f16), counted-vmcnt pipeline.

__global__ __launch_bounds__(256) void gemm_fc_kernel(
    const _Float16* __restrict__ xg,     // packed [KB_C][NPC][32]
    const _Float16* __restrict__ wt,     // packed [E][KB_C][HDIM][32]
    const float*    __restrict__ b_fc,   // [E][HDIM]
    const int*      __restrict__ tile_expert,
    const int*      __restrict__ mtiles,
    _Float16*       __restrict__ hb)     // packed [KB_H][NPC][32]
{
    // ---- XCD chunked swizzle (bijective: FC_TOTAL % 8 == 0) ----
    const unsigned flat = blockIdx.y * 32u + blockIdx.x;
    const unsigned logical = (flat & 7u) * FC_CHUNK + (flat >> 3);
    const int nt = logical & 31;          // 32 nt, fastest
    const int mt = logical >> 5;
    if (mt >= *mtiles) return;
    const int e  = tile_expert[mt];
    const int m0 = mt << 7, n0 = nt << 7;

    __shared__ _Float16 As0[128 * 32], Bs0[128 * 32];
    __shared__ _Float16 As1[128 * 32], Bs1[128 * 32];

    const int tid = threadIdx.x;
    const int lane = tid & 63, wv = tid >> 6;
    const int wm = (wv >> 1) * 64, wn = (wv & 1) * 64;
    const int l16 = lane & 15, lq = lane >> 4;

    const char* gA0 = (const char*)xg + (size_t)m0 * 64;
    const char* gB0 = (const char*)wt + ((size_t)e * KB_C * HDIM + n0) * 64;
    const int soff = wv * 2048 + lane * 16;
    char* lA0 = (char*)As0 + wv * 2048;  char* lB0 = (char*)Bs0 + wv * 2048;
    char* lA1 = (char*)As1 + wv * 2048;  char* lB1 = (char*)Bs1 + wv * 2048;

    f32x4 acc[4][4];
    #pragma unroll
    for (int i = 0; i < 4; ++i)
        #pragma unroll
        for (int j = 0; j < 4; ++j) { acc[i][j][0]=0.f; acc[i][j][1]=0.f; acc[i][j][2]=0.f; acc[i][j][3]=0.f; }

    PIPE_LOOP(0, KB_C, HDIM);

    float bias[4];
    #pragma unroll
    for (int j = 0; j < 4; ++j) bias[j] = b_fc[e * HDIM + n0 + wn + j * 16 + l16];
    #pragma unroll
    for (int i = 0; i < 4; ++i) {
        #pragma unroll
        for (int r = 0; r < 4; ++r) {
            int slot = m0 + wm + i * 16 + lq * 4 + r;   // D row = quad*4 + reg
            #pragma unroll
            for (int j = 0; j < 4; ++j) {
                int n = n0 + wn + j * 16 + l16;          // D col = lane&15
                float v = gelu_new(acc[i][j][r] + bias[j]);
                hb[((size_t)(n >> 5) * NPC + slot) * 32 + (n & 31)] = (_Float16)v;
            }
        }
    }
}

// ---------------- GEMM 2: y[tok] += gate * (hb @ wt_proj + b_proj), split-K=2 ----------------
// Counted-vmcnt pipeline like gemm_fc. XCD chunked swizzle.

__global__ __launch_bounds__(256) void gemm_proj_kernel(
    const _Float16* __restrict__ hb,     // packed [KB_H][NPC][32]
    const _Float16* __restrict__ wt,     // packed [E][KB_H][CDIM][32]
    const float*    __restrict__ b_proj, // [E][CDIM]
    const int*      __restrict__ pair_tok,
    const float*    __restrict__ pair_gate,
    const int*      __restrict__ tile_expert,
    const int*      __restrict__ mtiles,
    float*          __restrict__ y)      // [NTOK][CDIM]
{
    // ---- XCD chunked swizzle (bijective: PJ_TOTAL % 8 == 0) ----
    const unsigned flat = (blockIdx.z * MAXMT + blockIdx.y) * 8u + blockIdx.x;
    const unsigned logical = (flat & 7u) * PJ_CHUNK + (flat >> 3);
    const int nt = logical & 7;                       // 8 nt, fastest
    const unsigned t2 = logical >> 3;
    const int mt = t2 % MAXMT;
    const int ks = t2 / MAXMT;                        // split-K slice
    if (mt >= *mtiles) return;
    const int e  = tile_expert[mt];
    const int m0 = mt << 7, n0 = nt << 7;

    __shared__ _Float16 As0[128 * 32], Bs0[128 * 32];
    __shared__ _Float16 As1[128 * 32], Bs1[128 * 32];

    const int tid = threadIdx.x;
    const int lane = tid & 63, wv = tid >> 6;
    const int wm = (wv >> 1) * 64, wn = (wv & 1) * 64;
    const int l16 = lane & 15, lq = lane >> 4;

    const char* gA0 = (const char*)hb + (size_t)m0 * 64;
    const char* gB0 = (const char*)wt + ((size_t)e * KB_H * CDIM + n0) * 64;
    const int soff = wv * 2048 + lane * 16;
    char* lA0 = (char*)As0 + wv * 2048;  char* lB0 = (char*)Bs0 + wv * 2048;
    char* lA1 = (char*)As1 + wv * 2048;  char* lB1 = (char*)Bs1 + wv * 2048;

    f32x4 acc[4][4];
    #pragma unroll
    for (int i = 0; i < 4; ++i)
        #pragma unroll
        for (int j = 0; j < 4; ++j) { acc[i][j][0]=0.f; acc[i][j][1]=0.f; acc[i][j][2]=0.f; acc[i][j][3]=0.f; }

    const int kb_beg = ks * (KB_H / KSPLIT);
    const int kb_end = kb_beg + (KB_H / KSPLIT);
    PIPE_LOOP(kb_beg, kb_end, CDIM);

    float bias[4];
    #pragma unroll
    for (int j = 0; j < 4; ++j)
        bias[j] = (ks == 0) ? b_proj[e * CDIM + n0 + wn + j * 16 + l16] : 0.0f;
    #pragma unroll
    for (int i = 0; i < 4; ++i) {
        #pragma unroll
        for (int r = 0; r < 4; ++r) {
            int slot = m0 + wm + i * 16 + lq * 4 + r;
            float g  = pair_gate[slot];
            if (g != 0.0f) {
                int tok = pair_tok[slot];
                float* dst = y + (size_t)tok * CDIM + n0 + wn + l16;
                #pragma unroll
                for (int j = 0; j < 4; ++j)
                    atomicAdd(&dst[j * 16], (acc[i][j][r] + bias[j]) * g);
            }
        }
    }
}

// ---------------- launch ----------------

extern "C" void kernel_launch(void* const* d_in, const int* in_sizes, int n_in,
                              void* d_out, int out_size, void* d_ws, size_t ws_size,
                              hipStream_t stream) {
    const float* x   = (const float*)d_in[0];
    const float* rw  = (const float*)d_in[1];
    const float* wfc = (const float*)d_in[2];
    const float* bfc = (const float*)d_in[3];
    const float* wpj = (const float*)d_in[4];
    const float* bpj = (const float*)d_in[5];
    float* y = (float*)d_out;

    char* ws = (char*)d_ws;
    // workspace layout (bytes), total ~161.7 MB
    _Float16* xg  = (_Float16*)(ws);                    // 18,874,368  [KB_C][NPC][32]
    _Float16* hb  = (_Float16*)(ws + 18874368);         // 75,497,472  [KB_H][NPC][32]
    _Float16* wt  = (_Float16*)(ws + 94371840);         // 67,108,864  shared fc/proj
    char* meta = ws + 161480704;
    int*   pair_tok    = (int*)  (meta);                //  36,864
    float* pair_gate   = (float*)(meta + 36864);        //  36,864 (contiguous after pair_tok)
    int*   tok_e       = (int*)  (meta + 73728);        //  32,768
    float* tok_w       = (float*)(meta + 106496);       //  32,768
    int*   counts      = (int*)  (meta + 139264);       // 8
    int*   cursors     = counts + 8;                    // 8
    int*   mtiles      = cursors + 8;                   // 1 (+pad)
    int*   tile_expert = mtiles + 2;                    // 72

    hipMemsetAsync(y, 0, (size_t)NTOK * CDIM * sizeof(float), stream);
    zero_init<<<(2 * NPC) / 256, 256, 0, stream>>>((unsigned int*)pair_tok,
                                                   (unsigned int*)counts);

    router_kernel<<<1024, 256, 0, stream>>>(x, rw, tok_e, tok_w, counts);
    plan_kernel<<<1, 64, 0, stream>>>(counts, cursors, mtiles, tile_expert);
    assign_kernel<<<16, 256, 0, stream>>>(tok_e, tok_w, cursors, pair_tok, pair_gate);
    gather_x_kernel<<<KB_C * NPC * 4 / 256, 256, 0, stream>>>(x, pair_tok, xg);

    // fc: transpose w_fc -> wt, then GEMM into hb
    transpose_cvt_kernel<<<dim3(HDIM / 64, CDIM / 32, NEXP), 256, 0, stream>>>(wfc, wt, CDIM, HDIM);
    gemm_fc_kernel<<<dim3(HDIM / 128, MAXMT), 256, 0, stream>>>(
        xg, wt, bfc, tile_expert, mtiles, hb);

    // proj: transpose w_proj -> wt (reuse buffer), then GEMM into y
    transpose_cvt_kernel<<<dim3(CDIM / 64, HDIM / 32, NEXP), 256, 0, stream>>>(wpj, wt, HDIM, CDIM);
    gemm_proj_kernel<<<dim3(CDIM / 128, MAXMT, KSPLIT), 256, 0, stream>>>(
        hb, wt, bpj, pair_tok, pair_gate, tile_expert, mtiles, y);
}

// Round 5
// 681.533 us; speedup vs baseline: 1.0822x; 1.0229x over previous
//
#include <hip/hip_runtime.h>

// MoE top-2 layer, MI355X — round 7.
// r7 changes vs r6 (697 us; proj 153 stuck, ~250us hidden in transposes):
//   * DEATOMIZE proj (KSPLIT 2 -> 1): epilogue writes plain fp16 per-slot
//     rows out_s[slot][CDIM] (aliased over xg, dead after fc) instead of
//     18M fp32 atomicAdds into y. New combine kernel:
//     y[tok] = g0*out_s[slot0] + g1*out_s[slot1] via tok_slot inverse map
//     (stored in pair_gate's old meta space). r3 evidence: 2x atomics cost
//     +21us => ks2 atomics ~30-40us of proj's 153. Also drops y memset.
//   * Bigger transpose tiles: 64k x 64n per block (4x float4 loads + 2x
//     half8 stores per thread, LDS [64][69] to avoid read conflicts).
//     Old 32x64 tiles kept only ~64KB in flight per CU -> ~2TB/s; the two
//     transposes were ~250us of hidden time. 2x in-flight bytes -> ~BW-bound.
//   * Keep: counted-vmcnt dbuf pipeline (r6), XCD chunked swizzle (r4),
//     fast gelu (r3), packed fp16 [kb][row][32] operand layout.
//
// N=4096 tokens, C=1024, E=8, H=4096, top-2. NPC=9216 slot capacity.
// ws usage unchanged (~161.7 MB): out_s reuses xg's 18.87 MB exactly.

#define NTOK  4096
#define CDIM  1024
#define HDIM  4096
#define NEXP  8
#define NPC   9216
#define MAXMT 72
#define KB_C  32     // CDIM/32
#define KB_H  128    // HDIM/32

// swizzle chunk sizes (blocks per XCD)
#define FC_TOTAL (32 * MAXMT)          // 2304
#define FC_CHUNK (FC_TOTAL / 8)        // 288
#define PJ_TOTAL (8 * MAXMT)           // 576
#define PJ_CHUNK (PJ_TOTAL / 8)        // 72

typedef _Float16 half8 __attribute__((ext_vector_type(8)));
typedef float    f32x4 __attribute__((ext_vector_type(4)));

// async global->LDS, 16B per lane. LDS dest = wave-uniform base + lane*16;
// global source address is per-lane.
#define ASYNC_CP16(gp, lp)                                                         \
  __builtin_amdgcn_global_load_lds(                                                \
      (const __attribute__((address_space(1))) unsigned int*)(gp),                 \
      (__attribute__((address_space(3))) unsigned int*)(lp), 16, 0, 0)

// stage one 128x32 A-tile + 128x32 B-tile (8KB each) for K-block kb into the
// given wave-sliced LDS bases (4 gload_lds = 4 vmcnt events per wave).
#define STAGE(kb, LA, LB, BSTRIDE)                                                 \
  {                                                                                \
    const char* ga_ = gA0 + (size_t)(kb) * (NPC * 64) + soff;                      \
    const char* gb_ = gB0 + (size_t)(kb) * ((BSTRIDE) * 64) + soff;                \
    ASYNC_CP16(ga_,        LA);                                                    \
    ASYNC_CP16(ga_ + 1024, LA + 1024);                                             \
    ASYNC_CP16(gb_,        LB);                                                    \
    ASYNC_CP16(gb_ + 1024, LB + 1024);                                             \
  }

#define WAITV(N) asm volatile("s_waitcnt vmcnt(" #N ")" ::: "memory")
#define BAR()    __builtin_amdgcn_s_barrier()
#define SCHED0() __builtin_amdgcn_sched_barrier(0)

__device__ __forceinline__ void compute_step(
    const _Float16* __restrict__ AS, const _Float16* __restrict__ BS,
    int wm, int wn, int l16, int lq, f32x4 (&acc)[4][4])
{
    half8 af[4], bfv[4];
    #pragma unroll
    for (int i = 0; i < 4; ++i) af[i]  = *(const half8*)&AS[(wm + i * 16 + l16) * 32 + lq * 8];
    #pragma unroll
    for (int j = 0; j < 4; ++j) bfv[j] = *(const half8*)&BS[(wn + j * 16 + l16) * 32 + lq * 8];
    #pragma unroll
    for (int i = 0; i < 4; ++i)
        #pragma unroll
        for (int j = 0; j < 4; ++j)
            acc[i][j] = __builtin_amdgcn_mfma_f32_16x16x32_f16(af[i], bfv[j], acc[i][j], 0, 0, 0);
}

// Pipelined K-loop over [kb_beg, kb_end), NS even and >= 4.
// buf0 holds even (t-kb_beg), buf1 odd. vmcnt(4) = "my previous STAGE landed,
// the one after it may still fly". Tail peels with vmcnt(4) then vmcnt(0).
#define PIPE_LOOP(kb_beg, kb_end, BSTRIDE)                                         \
  {                                                                                \
    STAGE((kb_beg),     lA0, lB0, BSTRIDE);                                        \
    STAGE((kb_beg) + 1, lA1, lB1, BSTRIDE);                                        \
    for (int t = (kb_beg); t + 2 < (kb_end); t += 2) {                             \
        WAITV(4); BAR();                                                           \
        compute_step(As0, Bs0, wm, wn, l16, lq, acc);                              \
        SCHED0(); BAR();                                                           \
        STAGE(t + 2, lA0, lB0, BSTRIDE);                                           \
        WAITV(4); BAR();                                                           \
        compute_step(As1, Bs1, wm, wn, l16, lq, acc);                              \
        SCHED0(); BAR();                                                           \
        STAGE(t + 3, lA1, lB1, BSTRIDE);                                           \
    }                                                                              \
    WAITV(4); BAR();                                                               \
    compute_step(As0, Bs0, wm, wn, l16, lq, acc);                                  \
    SCHED0(); BAR();                                                               \
    WAITV(0); BAR();                                                               \
    compute_step(As1, Bs1, wm, wn, l16, lq, acc);                                  \
  }

__device__ __forceinline__ float gelu_new(float x) {
    // 0.5x(1+tanh(u)) == x * sigmoid(2u); robust at extremes.
    const float c = 0.7978845608028654f;  // sqrt(2/pi)
    float u = c * (x + 0.044715f * x * x * x);
    return x / (1.0f + __expf(-2.0f * u));
}

// ---------------- utility ----------------

__global__ void zero_init(unsigned int* __restrict__ pair_tok,
                          unsigned int* __restrict__ counts) {
    int i = blockIdx.x * 256 + threadIdx.x;
    if (i < NPC) pair_tok[i] = 0u;
    if (i < NEXP) counts[i] = 0u;
}

// ---------------- routing ----------------

__global__ __launch_bounds__(256) void router_kernel(
    const float* __restrict__ x, const float* __restrict__ rw,
    int* __restrict__ tok_e, float* __restrict__ tok_w, int* __restrict__ counts)
{
    int wave = threadIdx.x >> 6, lane = threadIdx.x & 63;
    int n = blockIdx.x * 4 + wave;
    const float* xr = x + (size_t)n * CDIM;
    float acc[NEXP];
    #pragma unroll
    for (int e = 0; e < NEXP; ++e) acc[e] = 0.f;
    for (int c = lane; c < CDIM; c += 64) {
        float xv = xr[c];
        #pragma unroll
        for (int e = 0; e < NEXP; ++e) acc[e] = fmaf(xv, rw[e * CDIM + c], acc[e]);
    }
    #pragma unroll
    for (int e = 0; e < NEXP; ++e) {
        float v = acc[e];
        #pragma unroll
        for (int off = 32; off > 0; off >>= 1) v += __shfl_down(v, off);
        acc[e] = v;
    }
    if (lane == 0) {
        float l0 = -3.0e38f, l1 = -3.0e38f; int b0 = 0, b1 = 0;
        #pragma unroll
        for (int e = 0; e < NEXP; ++e) {
            float v = acc[e];
            if (v > l0)      { l1 = l0; b1 = b0; l0 = v; b0 = e; }
            else if (v > l1) { l1 = v; b1 = e; }
        }
        float t  = expf(l1 - l0);            // l1 <= l0, stable
        float w0 = 1.f / (1.f + t);
        float w1 = t  / (1.f + t);
        tok_e[n * 2]     = b0;  tok_e[n * 2 + 1] = b1;
        tok_w[n * 2]     = w0;  tok_w[n * 2 + 1] = w1;
        atomicAdd(&counts[b0], 1);
        atomicAdd(&counts[b1], 1);
    }
}

__global__ void plan_kernel(const int* __restrict__ counts, int* __restrict__ cursors,
                            int* __restrict__ mtiles, int* __restrict__ tile_expert)
{
    if (threadIdx.x == 0 && blockIdx.x == 0) {
        int b = 0;
        for (int e = 0; e < NEXP; ++e) {
            cursors[e] = b;
            int tiles = (counts[e] + 127) >> 7;
            for (int t = 0; t < tiles; ++t) tile_expert[(b >> 7) + t] = e;
            b += tiles << 7;
        }
        *mtiles = b >> 7;
        for (int t = b >> 7; t < MAXMT; ++t) tile_expert[t] = 0;
    }
}

__global__ void assign_kernel(const int* __restrict__ tok_e,
                              int* __restrict__ cursors,
                              int* __restrict__ pair_tok, int* __restrict__ tok_slot)
{
    int n = blockIdx.x * 256 + threadIdx.x;  // exactly NTOK threads
    #pragma unroll
    for (int k = 0; k < 2; ++k) {
        int e = tok_e[n * 2 + k];
        int slot = atomicAdd(&cursors[e], 1);
        pair_tok[slot]     = n;
        tok_slot[n * 2 + k] = slot;
    }
}

// ---------------- A gather+convert into packed layout ----------------
// xg[kb][slot][kk] = fp16(x[pair_tok[slot]][kb*32+kk]); pad slots -> token 0.

__global__ __launch_bounds__(256) void gather_x_kernel(
    const float* __restrict__ x, const int* __restrict__ pair_tok,
    _Float16* __restrict__ xg)
{
    int o = blockIdx.x * 256 + threadIdx.x;          // KB_C * NPC * 4 threads
    int kb   = o / (NPC * 4);
    int rem  = o - kb * (NPC * 4);
    int slot = rem >> 2;
    int c    = (rem & 3) * 8;
    int tok  = pair_tok[slot];
    const float* src = x + (size_t)tok * CDIM + kb * 32 + c;
    float4 a = *(const float4*)src;
    float4 b = *(const float4*)(src + 4);
    half8 h;
    h[0] = (_Float16)a.x; h[1] = (_Float16)a.y; h[2] = (_Float16)a.z; h[3] = (_Float16)a.w;
    h[4] = (_Float16)b.x; h[5] = (_Float16)b.y; h[6] = (_Float16)b.z; h[7] = (_Float16)b.w;
    *(half8*)(xg + ((size_t)kb * NPC + slot) * 32 + c) = h;
}

// ---------------- weight transpose+convert ----------------
// w [E][K][N] fp32  ->  wt [E][K/32][N][32] fp16  (wt[e][kb][n][kk] = w[e][kb*32+kk][n])
// Block handles 64k x 64n tile via LDS (16KB read, 8KB write per block).
// LDS row pad 69 words: read side c2-groups land on distinct bank octets.

__global__ __launch_bounds__(256) void transpose_cvt_kernel(
    const float* __restrict__ w, _Float16* __restrict__ wt, int K, int N)
{
    __shared__ float tile[64][69];
    const int e = blockIdx.z, k0 = blockIdx.y * 64, n0 = blockIdx.x * 64;
    const float* src = w + ((size_t)e * K + k0) * N + n0;
    const int t = threadIdx.x;
    #pragma unroll
    for (int q = 0; q < 4; ++q) {                    // 1024 float4 = 64x64 floats
        int f = t + 256 * q;
        int k = f >> 4, nc = (f & 15) * 4;
        *(float4*)&tile[k][nc] = *(const float4*)(src + (size_t)k * N + nc);
    }
    __syncthreads();
    const int n = t >> 2, c2 = (t & 3) * 8;
    const int KB = K >> 5, kb0 = k0 >> 5;
    #pragma unroll
    for (int h2 = 0; h2 < 2; ++h2) {
        half8 h;
        #pragma unroll
        for (int q = 0; q < 8; ++q) h[q] = (_Float16)tile[h2 * 32 + c2 + q][n];
        *(half8*)(wt + (((size_t)e * KB + kb0 + h2) * N + (n0 + n)) * 32 + c2) = h;
    }
}

// ---------------- GEMM 1: hb = gelu(xg @ wt_fc + b_fc)  (packed in/out) ----------------
// 128x128 tile, BK=32, 4 waves x (4x4 mfma_f32_16x16x32_f16), counted-vmcnt pipeline.

__global__ __launch_bounds__(256) void gemm_fc_kernel(
    const _Float16* __restrict__ xg,     // packed [KB_C][NPC][32]
    const _Float16* __restrict__ wt,     // packed [E][KB_C][HDIM][32]
    const float*    __restrict__ b_fc,   // [E][HDIM]
    const int*      __restrict__ tile_expert,
    const int*      __restrict__ mtiles,
    _Float16*       __restrict__ hb)     // packed [KB_H][NPC][32]
{
    // ---- XCD chunked swizzle (bijective: FC_TOTAL % 8 == 0) ----
    const unsigned flat = blockIdx.y * 32u + blockIdx.x;
    const unsigned logical = (flat & 7u) * FC_CHUNK + (flat >> 3);
    const int nt = logical & 31;          // 32 nt, fastest
    const int mt = logical >> 5;
    if (mt >= *mtiles) return;
    const int e  = tile_expert[mt];
    const int m0 = mt << 7, n0 = nt << 7;

    __shared__ _Float16 As0[128 * 32], Bs0[128 * 32];
    __shared__ _Float16 As1[128 * 32], Bs1[128 * 32];

    const int tid = threadIdx.x;
    const int lane = tid & 63, wv = tid >> 6;
    const int wm = (wv >> 1) * 64, wn = (wv & 1) * 64;
    const int l16 = lane & 15, lq = lane >> 4;

    const char* gA0 = (const char*)xg + (size_t)m0 * 64;
    const char* gB0 = (const char*)wt + ((size_t)e * KB_C * HDIM + n0) * 64;
    const int soff = wv * 2048 + lane * 16;
    char* lA0 = (char*)As0 + wv * 2048;  char* lB0 = (char*)Bs0 + wv * 2048;
    char* lA1 = (char*)As1 + wv * 2048;  char* lB1 = (char*)Bs1 + wv * 2048;

    f32x4 acc[4][4];
    #pragma unroll
    for (int i = 0; i < 4; ++i)
        #pragma unroll
        for (int j = 0; j < 4; ++j) { acc[i][j][0]=0.f; acc[i][j][1]=0.f; acc[i][j][2]=0.f; acc[i][j][3]=0.f; }

    PIPE_LOOP(0, KB_C, HDIM);

    float bias[4];
    #pragma unroll
    for (int j = 0; j < 4; ++j) bias[j] = b_fc[e * HDIM + n0 + wn + j * 16 + l16];
    #pragma unroll
    for (int i = 0; i < 4; ++i) {
        #pragma unroll
        for (int r = 0; r < 4; ++r) {
            int slot = m0 + wm + i * 16 + lq * 4 + r;   // D row = quad*4 + reg
            #pragma unroll
            for (int j = 0; j < 4; ++j) {
                int n = n0 + wn + j * 16 + l16;          // D col = lane&15
                float v = gelu_new(acc[i][j][r] + bias[j]);
                hb[((size_t)(n >> 5) * NPC + slot) * 32 + (n & 31)] = (_Float16)v;
            }
        }
    }
}

// ---------------- GEMM 2: out_s[slot] = hb @ wt_proj + b_proj  (no atomics) ----------------
// K=4096 full depth per block (no split-K). Plain fp16 stores to per-slot rows.

__global__ __launch_bounds__(256) void gemm_proj_kernel(
    const _Float16* __restrict__ hb,     // packed [KB_H][NPC][32]
    const _Float16* __restrict__ wt,     // packed [E][KB_H][CDIM][32]
    const float*    __restrict__ b_proj, // [E][CDIM]
    const int*      __restrict__ tile_expert,
    const int*      __restrict__ mtiles,
    _Float16*       __restrict__ out_s)  // [NPC][CDIM] fp16 (aliases xg)
{
    // ---- XCD chunked swizzle (bijective: PJ_TOTAL % 8 == 0) ----
    const unsigned flat = blockIdx.y * 8u + blockIdx.x;
    const unsigned logical = (flat & 7u) * PJ_CHUNK + (flat >> 3);
    const int nt = logical & 7;                       // 8 nt, fastest
    const int mt = logical >> 3;
    if (mt >= *mtiles) return;
    const int e  = tile_expert[mt];
    const int m0 = mt << 7, n0 = nt << 7;

    __shared__ _Float16 As0[128 * 32], Bs0[128 * 32];
    __shared__ _Float16 As1[128 * 32], Bs1[128 * 32];

    const int tid = threadIdx.x;
    const int lane = tid & 63, wv = tid >> 6;
    const int wm = (wv >> 1) * 64, wn = (wv & 1) * 64;
    const int l16 = lane & 15, lq = lane >> 4;

    const char* gA0 = (const char*)hb + (size_t)m0 * 64;
    const char* gB0 = (const char*)wt + ((size_t)e * KB_H * CDIM + n0) * 64;
    const int soff = wv * 2048 + lane * 16;
    char* lA0 = (char*)As0 + wv * 2048;  char* lB0 = (char*)Bs0 + wv * 2048;
    char* lA1 = (char*)As1 + wv * 2048;  char* lB1 = (char*)Bs1 + wv * 2048;

    f32x4 acc[4][4];
    #pragma unroll
    for (int i = 0; i < 4; ++i)
        #pragma unroll
        for (int j = 0; j < 4; ++j) { acc[i][j][0]=0.f; acc[i][j][1]=0.f; acc[i][j][2]=0.f; acc[i][j][3]=0.f; }

    PIPE_LOOP(0, KB_H, CDIM);

    float bias[4];
    #pragma unroll
    for (int j = 0; j < 4; ++j) bias[j] = b_proj[e * CDIM + n0 + wn + j * 16 + l16];
    #pragma unroll
    for (int i = 0; i < 4; ++i) {
        #pragma unroll
        for (int r = 0; r < 4; ++r) {
            int slot = m0 + wm + i * 16 + lq * 4 + r;
            _Float16* dst = out_s + (size_t)slot * CDIM + n0 + wn + l16;
            #pragma unroll
            for (int j = 0; j < 4; ++j)
                dst[j * 16] = (_Float16)(acc[i][j][r] + bias[j]);
        }
    }
}

// ---------------- combine: y[tok] = g0*out_s[slot0] + g1*out_s[slot1] ----------------

__global__ __launch_bounds__(256) void combine_kernel(
    const _Float16* __restrict__ out_s,  // [NPC][CDIM]
    const int*      __restrict__ tok_slot, // [NTOK][2]
    const float*    __restrict__ tok_w,    // [NTOK][2]
    float*          __restrict__ y)        // [NTOK][CDIM]
{
    int idx = blockIdx.x * 256 + threadIdx.x;    // NTOK * (CDIM/8) threads
    int n  = idx >> 7;                            // 128 threads per token
    int c8 = (idx & 127) * 8;
    int s0 = tok_slot[n * 2], s1 = tok_slot[n * 2 + 1];
    float g0 = tok_w[n * 2], g1 = tok_w[n * 2 + 1];
    half8 o0 = *(const half8*)(out_s + (size_t)s0 * CDIM + c8);
    half8 o1 = *(const half8*)(out_s + (size_t)s1 * CDIM + c8);
    float4 a, b;
    a.x = g0 * (float)o0[0] + g1 * (float)o1[0];
    a.y = g0 * (float)o0[1] + g1 * (float)o1[1];
    a.z = g0 * (float)o0[2] + g1 * (float)o1[2];
    a.w = g0 * (float)o0[3] + g1 * (float)o1[3];
    b.x = g0 * (float)o0[4] + g1 * (float)o1[4];
    b.y = g0 * (float)o0[5] + g1 * (float)o1[5];
    b.z = g0 * (float)o0[6] + g1 * (float)o1[6];
    b.w = g0 * (float)o0[7] + g1 * (float)o1[7];
    *(float4*)(y + (size_t)n * CDIM + c8)     = a;
    *(float4*)(y + (size_t)n * CDIM + c8 + 4) = b;
}

// ---------------- launch ----------------

extern "C" void kernel_launch(void* const* d_in, const int* in_sizes, int n_in,
                              void* d_out, int out_size, void* d_ws, size_t ws_size,
                              hipStream_t stream) {
    const float* x   = (const float*)d_in[0];
    const float* rw  = (const float*)d_in[1];
    const float* wfc = (const float*)d_in[2];
    const float* bfc = (const float*)d_in[3];
    const float* wpj = (const float*)d_in[4];
    const float* bpj = (const float*)d_in[5];
    float* y = (float*)d_out;

    char* ws = (char*)d_ws;
    // workspace layout (bytes), total ~161.7 MB
    _Float16* xg  = (_Float16*)(ws);                    // 18,874,368  [KB_C][NPC][32]
    _Float16* out_s = (_Float16*)(ws);                  // aliases xg: [NPC][CDIM] fp16
    _Float16* hb  = (_Float16*)(ws + 18874368);         // 75,497,472  [KB_H][NPC][32]
    _Float16* wt  = (_Float16*)(ws + 94371840);         // 67,108,864  shared fc/proj
    char* meta = ws + 161480704;
    int*   pair_tok    = (int*)  (meta);                //  36,864
    int*   tok_slot    = (int*)  (meta + 36864);        //  32,768 (pair_gate's old space)
    int*   tok_e       = (int*)  (meta + 73728);        //  32,768
    float* tok_w       = (float*)(meta + 106496);       //  32,768
    int*   counts      = (int*)  (meta + 139264);       // 8
    int*   cursors     = counts + 8;                    // 8
    int*   mtiles      = cursors + 8;                   // 1 (+pad)
    int*   tile_expert = mtiles + 2;                    // 72

    zero_init<<<(NPC + 255) / 256, 256, 0, stream>>>((unsigned int*)pair_tok,
                                                     (unsigned int*)counts);

    router_kernel<<<1024, 256, 0, stream>>>(x, rw, tok_e, tok_w, counts);
    plan_kernel<<<1, 64, 0, stream>>>(counts, cursors, mtiles, tile_expert);
    assign_kernel<<<16, 256, 0, stream>>>(tok_e, cursors, pair_tok, tok_slot);
    gather_x_kernel<<<KB_C * NPC * 4 / 256, 256, 0, stream>>>(x, pair_tok, xg);

    // fc: transpose w_fc -> wt, then GEMM into hb
    transpose_cvt_kernel<<<dim3(HDIM / 64, CDIM / 64, NEXP), 256, 0, stream>>>(wfc, wt, CDIM, HDIM);
    gemm_fc_kernel<<<dim3(HDIM / 128, MAXMT), 256, 0, stream>>>(
        xg, wt, bfc, tile_expert, mtiles, hb);

    // proj: transpose w_proj -> wt (reuse buffer), GEMM into out_s (xg dead), combine
    transpose_cvt_kernel<<<dim3(CDIM / 64, HDIM / 64, NEXP), 256, 0, stream>>>(wpj, wt, HDIM, CDIM);
    gemm_proj_kernel<<<dim3(CDIM / 128, MAXMT), 256, 0, stream>>>(
        hb, wt, bpj, tile_expert, mtiles, out_s);
    combine_kernel<<<NTOK * (CDIM / 8) / 256, 256, 0, stream>>>(out_s, tok_slot, tok_w, y);
}